// Round 7
// baseline (570.906 us; speedup 1.0000x reference)
//
#include <hip/hip_runtime.h>
#include <cstdint>

constexpr int NN = 100000;   // nodes
constexpr int NE = 1600000;  // edges
constexpr int FIN = 512;
constexpr int HID = 128;
constexpr int NCLS = 6;
constexpr int EPAD = NE + 7 * NN;   // upper bound on pad-to-8 CSR edges

typedef __attribute__((ext_vector_type(8))) short short8v;  // 8 bf16 (4 VGPR)
typedef __attribute__((ext_vector_type(4))) float f32x4;

__device__ __forceinline__ unsigned short f2bf(float f) {
    uint32_t u = __float_as_uint(f);
    uint32_t r = u + 0x7FFFu + ((u >> 16) & 1u);   // round-to-nearest-even
    return (unsigned short)(r >> 16);
}
__device__ __forceinline__ float bflo(uint32_t u) { return __uint_as_float(u << 16); }
__device__ __forceinline__ float bfhi(uint32_t u) { return __uint_as_float(u & 0xffff0000u); }

// async global -> LDS, 16B per lane; lds dest must be wave-uniform base
__device__ __forceinline__ void gl_lds16(const void* g, void* l) {
    __builtin_amdgcn_global_load_lds(
        (const __attribute__((address_space(1))) unsigned int*)(unsigned long long)g,
        (__attribute__((address_space(3))) unsigned int*)(unsigned int)(unsigned long long)l,
        16, 0, 0);
}

// ============ W1/W2/W3 fp32 -> fragment-ordered bf16, one launch ===========
__device__ __forceinline__ void cvt_body(const float* __restrict__ W,
                                         unsigned short* __restrict__ Bp, int t) {
    const int lane = t & 63;
    const int fi = t >> 6;
    const int n = fi & 7, ks = fi >> 3;
    const int krow = ks * 32 + (lane >> 4) * 8;
    const int col = n * 16 + (lane & 15);
    short8v sv;
    #pragma unroll
    for (int j = 0; j < 8; ++j) sv[j] = (short)f2bf(W[(size_t)(krow + j) * HID + col]);
    *(short8v*)&Bp[(size_t)t * 8] = sv;
}

__global__ void cvt_w3(const float* __restrict__ W1, const float* __restrict__ W2,
                       const float* __restrict__ W3,
                       unsigned short* __restrict__ Bp1, unsigned short* __restrict__ Bp2,
                       unsigned short* __restrict__ Bp3) {
    const int t = blockIdx.x * blockDim.x + threadIdx.x;
    constexpr int T1 = (FIN / 32) * 8 * 64;       // 8192
    constexpr int T2 = (HID / 32) * 8 * 64;       // 2048
    if (t < T1)                cvt_body(W1, Bp1, t);
    else if (t < T1 + T2)      cvt_body(W2, Bp2, t - T1);
    else if (t < T1 + 2 * T2)  cvt_body(W3, Bp3, t - T1 - T2);
}

// ============ LDS-staged MFMA GEMM: Sc[8][NN][16](bf16) = A[M,K] @ Bp ======
// BM=160 rows/block, 5 waves x 32 rows, KS=32. Per-wave private LDS slices,
// NO barriers. B frags loaded FIRST each step so one counted vmcnt(NISS)
// covers B + current A buffer while next-tile DMAs stay in flight (T4).
// Output is chunk-major: Sc[n][r][lr]  (MFMA n-index == feature chunk).
template<int K, bool ABF>   // ABF: A is bf16 (else fp32)
__launch_bounds__(320)
__global__ void gemm_lds(const void* __restrict__ Av, const unsigned short* __restrict__ Bp,
                         unsigned short* __restrict__ Sc) {
    constexpr int BM    = 160;
    constexpr int KS    = 32;
    constexpr int EB    = ABF ? 2 : 4;       // element bytes
    constexpr int ROWB  = KS * EB;           // bytes per row window: 64 / 128
    constexpr int SLOTS = ROWB / 16;         // 4 / 8
    constexpr int SMSK  = SLOTS - 1;
    constexpr int CHUNK = BM * ROWB;         // 10240 / 20480
    constexpr int WBYT  = CHUNK / 5;         // bytes staged per wave: 2048 / 4096
    constexpr int NISS  = WBYT / 1024;       // DMA issues per wave per step: 2 / 4
    constexpr int NS    = K / KS;

    __shared__ __attribute__((aligned(16))) unsigned char lds[2 * CHUNK];

    const int tid  = threadIdx.x;
    const int lane = tid & 63;
    const int wave = tid >> 6;               // 0..4
    const int row0 = blockIdx.x * BM;
    const int lr   = lane & 15;
    const int kg   = lane >> 4;              // 0..3

    const unsigned char* Ab = (const unsigned char*)Av;
    const size_t rowbytes = (size_t)K * EB;

    // staging: per issue i, thread covers LDS byte Lw; src slot XOR-swizzled
    auto stage = [&](int bufsel, int ks) {
        const size_t kbyte = (size_t)ks * ROWB;
        #pragma unroll
        for (int i = 0; i < NISS; ++i) {
            const int Lw   = wave * WBYT + i * 1024 + lane * 16;
            const int row  = Lw / ROWB;
            const int slot = (Lw >> 4) & SMSK;
            const int src  = slot ^ (row & SMSK);
            const unsigned char* g = Ab + (size_t)(row0 + row) * rowbytes + kbyte + src * 16;
            void* l = (void*)&lds[bufsel * CHUNK + wave * WBYT + i * 1024];
            gl_lds16(g, l);
        }
    };

    f32x4 acc[2][8] = {};

    stage(0, 0);

    int cur = 0;
    for (int ks = 0; ks < NS; ++ks) {
        // ---- B fragments FIRST (so they're older than the stage DMAs) ----
        short8v bfr[8];
        const unsigned short* bb = Bp + ((size_t)ks * 8 * 64 + lane) * 8;
        #pragma unroll
        for (int n = 0; n < 8; ++n)
            bfr[n] = *reinterpret_cast<const short8v*>(bb + (size_t)n * 64 * 8);

        if (ks + 1 < NS) {
            stage(cur ^ 1, ks + 1);
            // drain everything except the NISS just-issued next-tile DMAs:
            // B frags of this step + current A buffer are then complete.
            asm volatile("s_waitcnt vmcnt(%0)" :: "i"(NISS) : "memory");
        } else {
            asm volatile("s_waitcnt vmcnt(0)" ::: "memory");
        }
        __builtin_amdgcn_sched_barrier(0);

        const unsigned char* base = &lds[cur * CHUNK];
        const int rA0 = wave * 32 + lr;
        const int rA1 = rA0 + 16;
        const int key = lr & SMSK;           // (rA0 & SMSK) == (rA1 & SMSK)

        short8v a0, a1;
        if constexpr (ABF) {
            a0 = *(const short8v*)(base + rA0 * ROWB + ((kg ^ key) * 16));
            a1 = *(const short8v*)(base + rA1 * ROWB + ((kg ^ key) * 16));
        } else {
            const float4 f00 = *(const float4*)(base + rA0 * ROWB + (((2 * kg + 0) ^ key) * 16));
            const float4 f01 = *(const float4*)(base + rA0 * ROWB + (((2 * kg + 1) ^ key) * 16));
            const float4 f10 = *(const float4*)(base + rA1 * ROWB + (((2 * kg + 0) ^ key) * 16));
            const float4 f11 = *(const float4*)(base + rA1 * ROWB + (((2 * kg + 1) ^ key) * 16));
            a0[0] = (short)f2bf(f00.x); a0[1] = (short)f2bf(f00.y);
            a0[2] = (short)f2bf(f00.z); a0[3] = (short)f2bf(f00.w);
            a0[4] = (short)f2bf(f01.x); a0[5] = (short)f2bf(f01.y);
            a0[6] = (short)f2bf(f01.z); a0[7] = (short)f2bf(f01.w);
            a1[0] = (short)f2bf(f10.x); a1[1] = (short)f2bf(f10.y);
            a1[2] = (short)f2bf(f10.z); a1[3] = (short)f2bf(f10.w);
            a1[4] = (short)f2bf(f11.x); a1[5] = (short)f2bf(f11.y);
            a1[6] = (short)f2bf(f11.z); a1[7] = (short)f2bf(f11.w);
        }

        #pragma unroll
        for (int n = 0; n < 8; ++n) {
            acc[0][n] = __builtin_amdgcn_mfma_f32_16x16x32_bf16(a0, bfr[n], acc[0][n], 0, 0, 0);
            acc[1][n] = __builtin_amdgcn_mfma_f32_16x16x32_bf16(a1, bfr[n], acc[1][n], 0, 0, 0);
        }
        cur ^= 1;
    }

    // chunk-major write: Sc[(n*NN + r)*16 + lr]
    #pragma unroll
    for (int m = 0; m < 2; ++m)
        #pragma unroll
        for (int n = 0; n < 8; ++n)
            #pragma unroll
            for (int i = 0; i < 4; ++i) {
                const int r = row0 + wave * 32 + m * 16 + kg * 4 + i;
                Sc[((size_t)n * NN + r) * 16 + lr] = f2bf(acc[m][n][i]);
            }
}

// ---------------- GEMM for W4 [128,6], bf16 H ------------------------------
__global__ void gemm_w4(const unsigned short* __restrict__ H, const float* __restrict__ W,
                        float* __restrict__ S, int M) {
    __shared__ float Ws[HID * NCLS];
    for (int i = threadIdx.x; i < HID * NCLS; i += blockDim.x) Ws[i] = W[i];
    __syncthreads();
    const int r = blockIdx.x * blockDim.x + threadIdx.x;
    if (r >= M) return;
    float acc[NCLS] = {};
    const unsigned short* h = &H[(size_t)r * HID];
    for (int k0 = 0; k0 < HID; k0 += 8) {
        const uint4 hv = *reinterpret_cast<const uint4*>(&h[k0]);
        float hf[8];
        hf[0] = bflo(hv.x); hf[1] = bfhi(hv.x);
        hf[2] = bflo(hv.y); hf[3] = bfhi(hv.y);
        hf[4] = bflo(hv.z); hf[5] = bfhi(hv.z);
        hf[6] = bflo(hv.w); hf[7] = bfhi(hv.w);
        #pragma unroll
        for (int u = 0; u < 8; ++u)
            #pragma unroll
            for (int j = 0; j < NCLS; ++j)
                acc[j] = fmaf(hf[u], Ws[(k0 + u) * NCLS + j], acc[j]);
    }
    #pragma unroll
    for (int j = 0; j < NCLS; ++j) S[(size_t)r * NCLS + j] = acc[j];
}

// ================= CSR construction (rows padded to %8) ====================
__global__ void hist_k(const int* __restrict__ erow, int* __restrict__ cnt) {
    const int e = blockIdx.x * blockDim.x + threadIdx.x;
    if (e < NE) atomicAdd(&cnt[erow[e]], 1);
}

__global__ void scan1_k(const int* __restrict__ in, int* __restrict__ out,
                        int* __restrict__ bsum, int n) {
    __shared__ int s[256];
    const int tid = threadIdx.x;
    const int gid = blockIdx.x * 256 + tid;
    const int v = (gid < NN) ? ((in[gid] + 7) & ~7) : 0;
    s[tid] = v;
    __syncthreads();
    for (int off = 1; off < 256; off <<= 1) {
        const int t = (tid >= off) ? s[tid - off] : 0;
        __syncthreads();
        s[tid] += t;
        __syncthreads();
    }
    if (gid < n) out[gid] = s[tid] - v;
    if (tid == 255) bsum[blockIdx.x] = s[255];
}

__global__ void scan2_k(int* __restrict__ bsum, int nb) {
    __shared__ int s[512];
    const int tid = threadIdx.x;
    const int v = (tid < nb) ? bsum[tid] : 0;
    s[tid] = v;
    __syncthreads();
    for (int off = 1; off < 512; off <<= 1) {
        const int t = (tid >= off) ? s[tid - off] : 0;
        __syncthreads();
        s[tid] += t;
        __syncthreads();
    }
    if (tid < nb) bsum[tid] = s[tid] - v;
}

__global__ void scan3_k(int* __restrict__ out, const int* __restrict__ bsum, int n) {
    const int gid = blockIdx.x * 256 + threadIdx.x;
    if (gid < n) out[gid] += bsum[blockIdx.x];
}

__global__ void scatter_k(const int* __restrict__ erow, const int* __restrict__ ecol,
                          const float* __restrict__ ew,
                          const int* __restrict__ row_ptr, int* __restrict__ cur,
                          int2* __restrict__ edges) {
    const int e = blockIdx.x * blockDim.x + threadIdx.x;
    if (e >= NE) return;
    const int r = erow[e];
    const int pos = row_ptr[r] + atomicAdd(&cur[r], 1);
    edges[pos] = make_int2(ecol[e], __float_as_int(ew[e]));
}

// zero only the pad slots (cnt[r]..row_ptr[r+1])
__global__ void pad_k(const int* __restrict__ row_ptr, const int* __restrict__ cur,
                      int2* __restrict__ edges) {
    const int r = blockIdx.x * blockDim.x + threadIdx.x;
    if (r >= NN) return;
    const int end = row_ptr[r + 1];
    for (int p = row_ptr[r] + cur[r]; p < end; ++p) edges[p] = make_int2(0, 0);
}

// ============ CSR SpMM, XCD-pinned feature chunks ==========================
// Sc chunk-major [8][NN][16]; chunk = blockIdx.x & 7 -> dispatch round-robin
// pins chunk k to XCD k whose L2 caches the 3.2MB slice. 8 lanes/row x 2
// feats (uint), 32 rows/block. Rows padded to %8 (pad edges col=0,w=0).
template<bool RELU>
__launch_bounds__(256)
__global__ void spmm_l2(const int* __restrict__ row_ptr,
                        const int2* __restrict__ edges,
                        const unsigned short* __restrict__ Sc,
                        const float* __restrict__ bias,
                        unsigned short* __restrict__ out) {
    const int chunk  = blockIdx.x & 7;
    const int rowblk = blockIdx.x >> 3;
    const int fl     = threadIdx.x & 7;       // 2 feats per lane
    const int rowg   = threadIdx.x >> 3;      // 0..31
    const int row    = rowblk * 32 + rowg;
    const int beg = row_ptr[row];
    const int end = row_ptr[row + 1];
    const unsigned short* S = Sc + (size_t)chunk * NN * 16 + fl * 2;
    const int f0 = chunk * 16 + fl * 2;

    const float2 bv = *reinterpret_cast<const float2*>(&bias[f0]);
    float2 a0 = bv, a1 = {0.f, 0.f}, a2 = {0.f, 0.f}, a3 = {0.f, 0.f};

    for (int j = beg; j < end; j += 8) {
        const int4 p0 = *reinterpret_cast<const int4*>(edges + j);
        const int4 p1 = *reinterpret_cast<const int4*>(edges + j + 2);
        const int4 p2 = *reinterpret_cast<const int4*>(edges + j + 4);
        const int4 p3 = *reinterpret_cast<const int4*>(edges + j + 6);
        const uint32_t s0 = *reinterpret_cast<const uint32_t*>(&S[(size_t)p0.x * 16]);
        const uint32_t s1 = *reinterpret_cast<const uint32_t*>(&S[(size_t)p0.z * 16]);
        const uint32_t s2 = *reinterpret_cast<const uint32_t*>(&S[(size_t)p1.x * 16]);
        const uint32_t s3 = *reinterpret_cast<const uint32_t*>(&S[(size_t)p1.z * 16]);
        const uint32_t s4 = *reinterpret_cast<const uint32_t*>(&S[(size_t)p2.x * 16]);
        const uint32_t s5 = *reinterpret_cast<const uint32_t*>(&S[(size_t)p2.z * 16]);
        const uint32_t s6 = *reinterpret_cast<const uint32_t*>(&S[(size_t)p3.x * 16]);
        const uint32_t s7 = *reinterpret_cast<const uint32_t*>(&S[(size_t)p3.z * 16]);
        const float w0 = __int_as_float(p0.y), w1 = __int_as_float(p0.w);
        const float w2 = __int_as_float(p1.y), w3 = __int_as_float(p1.w);
        const float w4 = __int_as_float(p2.y), w5 = __int_as_float(p2.w);
        const float w6 = __int_as_float(p3.y), w7 = __int_as_float(p3.w);
        a0.x = fmaf(bflo(s0), w0, a0.x); a0.y = fmaf(bfhi(s0), w0, a0.y);
        a1.x = fmaf(bflo(s1), w1, a1.x); a1.y = fmaf(bfhi(s1), w1, a1.y);
        a2.x = fmaf(bflo(s2), w2, a2.x); a2.y = fmaf(bfhi(s2), w2, a2.y);
        a3.x = fmaf(bflo(s3), w3, a3.x); a3.y = fmaf(bfhi(s3), w3, a3.y);
        a0.x = fmaf(bflo(s4), w4, a0.x); a0.y = fmaf(bfhi(s4), w4, a0.y);
        a1.x = fmaf(bflo(s5), w5, a1.x); a1.y = fmaf(bfhi(s5), w5, a1.y);
        a2.x = fmaf(bflo(s6), w6, a2.x); a2.y = fmaf(bfhi(s6), w6, a2.y);
        a3.x = fmaf(bflo(s7), w7, a3.x); a3.y = fmaf(bfhi(s7), w7, a3.y);
    }
    float fx = (a0.x + a1.x) + (a2.x + a3.x);
    float fy = (a0.y + a1.y) + (a2.y + a3.y);
    if (RELU) { fx = fmaxf(fx, 0.f); fy = fmaxf(fy, 0.f); }
    const uint32_t o = (uint32_t)f2bf(fx) | ((uint32_t)f2bf(fy) << 16);
    *reinterpret_cast<uint32_t*>(&out[(size_t)row * HID + f0]) = o;
}

// ============ CSR SpMM, F=6, fp32, 16 lanes/row ============================
__launch_bounds__(256)
__global__ void spmm6(const int* __restrict__ row_ptr,
                      const int2* __restrict__ edges,
                      const float* __restrict__ S,
                      const float* __restrict__ bias,
                      float* __restrict__ out) {
    const int t = blockIdx.x * blockDim.x + threadIdx.x;
    const int row = t >> 4;
    const int sl = t & 15;
    if (row >= NN) return;
    const int beg = row_ptr[row];
    const int end = row_ptr[row + 1];
    float acc[NCLS] = {};
    for (int j = beg + sl; j < end; j += 16) {
        const int2 e = edges[j];
        const float w = __int_as_float(e.y);
        const float* s = &S[(size_t)e.x * NCLS];
        #pragma unroll
        for (int k = 0; k < NCLS; ++k) acc[k] = fmaf(s[k], w, acc[k]);
    }
    #pragma unroll
    for (int off = 8; off > 0; off >>= 1)
        #pragma unroll
        for (int k = 0; k < NCLS; ++k) acc[k] += __shfl_xor(acc[k], off, 64);
    if (sl == 0) {
        #pragma unroll
        for (int k = 0; k < NCLS; ++k) out[(size_t)row * NCLS + k] = acc[k] + bias[k];
    }
}

extern "C" void kernel_launch(void* const* d_in, const int* in_sizes, int n_in,
                              void* d_out, int out_size, void* d_ws, size_t ws_size,
                              hipStream_t stream) {
    const float* x    = (const float*)d_in[0];
    const int*   erow = (const int*)d_in[1];
    const int*   ecol = (const int*)d_in[2];
    const float* ew   = (const float*)d_in[3];
    const float* W1 = (const float*)d_in[4];  const float* b1 = (const float*)d_in[5];
    const float* W2 = (const float*)d_in[6];  const float* b2 = (const float*)d_in[7];
    const float* W3 = (const float*)d_in[8];  const float* b3 = (const float*)d_in[9];
    const float* W4 = (const float*)d_in[10]; const float* b4 = (const float*)d_in[11];
    float* out = (float*)d_out;

    // ---- workspace layout ----
    int2*           edges_s = (int2*)d_ws;                          // EPAD*8B
    unsigned short* sup16   = (unsigned short*)(edges_s + EPAD);    // NN*128*2B (chunk-major)
    unsigned short* h16     = sup16 + (size_t)NN * HID;             // NN*128*2B (row-major)
    float*          sup6    = (float*)(h16 + (size_t)NN * HID);     // NN*6*4B
    unsigned short* Bp1     = (unsigned short*)(sup6 + (size_t)NN * NCLS);
    unsigned short* Bp2     = Bp1 + (size_t)FIN * HID;
    unsigned short* Bp3     = Bp2 + (size_t)HID * HID;
    int*            row_ptr = (int*)(Bp3 + (size_t)HID * HID);      // NN+1
    int*            row_cnt = row_ptr + (NN + 1);                   // NN (hist)
    int*            row_cur = row_cnt + NN;                         // NN (scatter cursor)
    int*            bsum    = row_cur + NN;                         // 512

    const dim3 blk(256);
    const int  g_edge = (NE + 255) / 256;
    const int  NB = (NN + 1 + 255) / 256;

    // ---- weights -> fragment-ordered bf16 ----
    cvt_w3<<<(12288 + 255) / 256, blk, 0, stream>>>(W1, W2, W3, Bp1, Bp2, Bp3);

    // ---- build CSR (rows padded to %8) ----
    hipMemsetAsync(row_cnt, 0, (size_t)2 * NN * sizeof(int), stream);  // cnt + cur
    hist_k<<<g_edge, blk, 0, stream>>>(erow, row_cnt);
    scan1_k<<<NB, blk, 0, stream>>>(row_cnt, row_ptr, bsum, NN + 1);
    scan2_k<<<1, 512, 0, stream>>>(bsum, NB);
    scan3_k<<<NB, blk, 0, stream>>>(row_ptr, bsum, NN + 1);
    scatter_k<<<g_edge, blk, 0, stream>>>(erow, ecol, ew, row_ptr, row_cur, edges_s);
    pad_k<<<(NN + 255) / 256, blk, 0, stream>>>(row_ptr, row_cur, edges_s);

    const int g_gemm = NN / 160;            // 625, exact
    const int g_spmm = 8 * (NN / 32);       // 25000: chunk = bid & 7

    // ---- layer 1 ----
    gemm_lds<FIN, false><<<g_gemm, dim3(320), 0, stream>>>(x, Bp1, sup16);
    spmm_l2<true><<<g_spmm, blk, 0, stream>>>(row_ptr, edges_s, sup16, b1, h16);
    // ---- layer 2 ----
    gemm_lds<HID, true><<<g_gemm, dim3(320), 0, stream>>>(h16, Bp2, sup16);
    spmm_l2<true><<<g_spmm, blk, 0, stream>>>(row_ptr, edges_s, sup16, b2, h16);
    // ---- layer 3 ----
    gemm_lds<HID, true><<<g_gemm, dim3(320), 0, stream>>>(h16, Bp3, sup16);
    spmm_l2<true><<<g_spmm, blk, 0, stream>>>(row_ptr, edges_s, sup16, b3, h16);
    // ---- layer 4 ----
    gemm_w4<<<(NN + 255) / 256, blk, 0, stream>>>(h16, W4, sup6, NN);
    spmm6<<<(NN * 16 + 255) / 256, blk, 0, stream>>>(row_ptr, edges_s, sup6, b4, out);
}

// Round 8
// 459.354 us; speedup vs baseline: 1.2428x; 1.2428x over previous
//
#include <hip/hip_runtime.h>
#include <cstdint>

constexpr int NN = 100000;   // nodes
constexpr int NE = 1600000;  // edges
constexpr int FIN = 512;
constexpr int HID = 128;
constexpr int NCLS = 6;
constexpr int EPAD = NE + 7 * NN;   // upper bound on pad-to-8 CSR edges

typedef __attribute__((ext_vector_type(8))) short short8v;  // 8 bf16 (4 VGPR)
typedef __attribute__((ext_vector_type(4))) float f32x4;

__device__ __forceinline__ unsigned short f2bf(float f) {
    uint32_t u = __float_as_uint(f);
    uint32_t r = u + 0x7FFFu + ((u >> 16) & 1u);   // round-to-nearest-even
    return (unsigned short)(r >> 16);
}
__device__ __forceinline__ float bflo(uint32_t u) { return __uint_as_float(u << 16); }
__device__ __forceinline__ float bfhi(uint32_t u) { return __uint_as_float(u & 0xffff0000u); }

// async global -> LDS, 16B per lane; lds dest must be wave-uniform base
__device__ __forceinline__ void gl_lds16(const void* g, void* l) {
    __builtin_amdgcn_global_load_lds(
        (const __attribute__((address_space(1))) unsigned int*)(unsigned long long)g,
        (__attribute__((address_space(3))) unsigned int*)(unsigned int)(unsigned long long)l,
        16, 0, 0);
}

// ============ W1/W2/W3 fp32 -> fragment-ordered bf16, one launch ===========
__device__ __forceinline__ void cvt_body(const float* __restrict__ W,
                                         unsigned short* __restrict__ Bp, int t) {
    const int lane = t & 63;
    const int fi = t >> 6;
    const int n = fi & 7, ks = fi >> 3;
    const int krow = ks * 32 + (lane >> 4) * 8;
    const int col = n * 16 + (lane & 15);
    short8v sv;
    #pragma unroll
    for (int j = 0; j < 8; ++j) sv[j] = (short)f2bf(W[(size_t)(krow + j) * HID + col]);
    *(short8v*)&Bp[(size_t)t * 8] = sv;
}

__global__ void cvt_w3(const float* __restrict__ W1, const float* __restrict__ W2,
                       const float* __restrict__ W3,
                       unsigned short* __restrict__ Bp1, unsigned short* __restrict__ Bp2,
                       unsigned short* __restrict__ Bp3) {
    const int t = blockIdx.x * blockDim.x + threadIdx.x;
    constexpr int T1 = (FIN / 32) * 8 * 64;       // 8192
    constexpr int T2 = (HID / 32) * 8 * 64;       // 2048
    if (t < T1)                cvt_body(W1, Bp1, t);
    else if (t < T1 + T2)      cvt_body(W2, Bp2, t - T1);
    else if (t < T1 + 2 * T2)  cvt_body(W3, Bp3, t - T1 - T2);
}

// ============ LDS-staged MFMA GEMM: C[M,128](bf16) = A[M,K] @ Bp ===========
// BM=160 rows/block, 5 waves x 32 rows, KS=32. Per-wave private LDS slices,
// NO barriers. B frags loaded FIRST each step so one counted vmcnt(NISS)
// covers B + current A buffer while next-tile DMAs stay in flight (T4).
template<int K, bool ABF>   // ABF: A is bf16 (else fp32)
__launch_bounds__(320)
__global__ void gemm_lds(const void* __restrict__ Av, const unsigned short* __restrict__ Bp,
                         unsigned short* __restrict__ C) {
    constexpr int BM    = 160;
    constexpr int KS    = 32;
    constexpr int EB    = ABF ? 2 : 4;       // element bytes
    constexpr int ROWB  = KS * EB;           // bytes per row window: 64 / 128
    constexpr int SLOTS = ROWB / 16;         // 4 / 8
    constexpr int SMSK  = SLOTS - 1;
    constexpr int CHUNK = BM * ROWB;         // 10240 / 20480
    constexpr int WBYT  = CHUNK / 5;         // bytes staged per wave: 2048 / 4096
    constexpr int NISS  = WBYT / 1024;       // DMA issues per wave per step: 2 / 4
    constexpr int NS    = K / KS;

    __shared__ __attribute__((aligned(16))) unsigned char lds[2 * CHUNK];

    const int tid  = threadIdx.x;
    const int lane = tid & 63;
    const int wave = tid >> 6;               // 0..4
    const int row0 = blockIdx.x * BM;
    const int lr   = lane & 15;
    const int kg   = lane >> 4;              // 0..3

    const unsigned char* Ab = (const unsigned char*)Av;
    const size_t rowbytes = (size_t)K * EB;

    // staging: per issue i, thread covers LDS byte Lw; src slot XOR-swizzled
    auto stage = [&](int bufsel, int ks) {
        const size_t kbyte = (size_t)ks * ROWB;
        #pragma unroll
        for (int i = 0; i < NISS; ++i) {
            const int Lw   = wave * WBYT + i * 1024 + lane * 16;
            const int row  = Lw / ROWB;
            const int slot = (Lw >> 4) & SMSK;
            const int src  = slot ^ (row & SMSK);
            const unsigned char* g = Ab + (size_t)(row0 + row) * rowbytes + kbyte + src * 16;
            void* l = (void*)&lds[bufsel * CHUNK + wave * WBYT + i * 1024];
            gl_lds16(g, l);
        }
    };

    f32x4 acc[2][8] = {};

    stage(0, 0);

    int cur = 0;
    for (int ks = 0; ks < NS; ++ks) {
        // ---- B fragments FIRST (so they're older than the stage DMAs) ----
        short8v bfr[8];
        const unsigned short* bb = Bp + ((size_t)ks * 8 * 64 + lane) * 8;
        #pragma unroll
        for (int n = 0; n < 8; ++n)
            bfr[n] = *reinterpret_cast<const short8v*>(bb + (size_t)n * 64 * 8);

        if (ks + 1 < NS) {
            stage(cur ^ 1, ks + 1);
            // drain everything except the NISS just-issued next-tile DMAs:
            // B frags of this step + current A buffer are then complete.
            asm volatile("s_waitcnt vmcnt(%0)" :: "i"(NISS) : "memory");
        } else {
            asm volatile("s_waitcnt vmcnt(0)" ::: "memory");
        }
        __builtin_amdgcn_sched_barrier(0);

        const unsigned char* base = &lds[cur * CHUNK];
        const int rA0 = wave * 32 + lr;
        const int rA1 = rA0 + 16;
        const int key = lr & SMSK;           // (rA0 & SMSK) == (rA1 & SMSK)

        short8v a0, a1;
        if constexpr (ABF) {
            a0 = *(const short8v*)(base + rA0 * ROWB + ((kg ^ key) * 16));
            a1 = *(const short8v*)(base + rA1 * ROWB + ((kg ^ key) * 16));
        } else {
            const float4 f00 = *(const float4*)(base + rA0 * ROWB + (((2 * kg + 0) ^ key) * 16));
            const float4 f01 = *(const float4*)(base + rA0 * ROWB + (((2 * kg + 1) ^ key) * 16));
            const float4 f10 = *(const float4*)(base + rA1 * ROWB + (((2 * kg + 0) ^ key) * 16));
            const float4 f11 = *(const float4*)(base + rA1 * ROWB + (((2 * kg + 1) ^ key) * 16));
            a0[0] = (short)f2bf(f00.x); a0[1] = (short)f2bf(f00.y);
            a0[2] = (short)f2bf(f00.z); a0[3] = (short)f2bf(f00.w);
            a0[4] = (short)f2bf(f01.x); a0[5] = (short)f2bf(f01.y);
            a0[6] = (short)f2bf(f01.z); a0[7] = (short)f2bf(f01.w);
            a1[0] = (short)f2bf(f10.x); a1[1] = (short)f2bf(f10.y);
            a1[2] = (short)f2bf(f10.z); a1[3] = (short)f2bf(f10.w);
            a1[4] = (short)f2bf(f11.x); a1[5] = (short)f2bf(f11.y);
            a1[6] = (short)f2bf(f11.z); a1[7] = (short)f2bf(f11.w);
        }

        #pragma unroll
        for (int n = 0; n < 8; ++n) {
            acc[0][n] = __builtin_amdgcn_mfma_f32_16x16x32_bf16(a0, bfr[n], acc[0][n], 0, 0, 0);
            acc[1][n] = __builtin_amdgcn_mfma_f32_16x16x32_bf16(a1, bfr[n], acc[1][n], 0, 0, 0);
        }
        cur ^= 1;
    }

    // C/D layout: col = lane&15, row = (lane>>4)*4 + reg   [m89-verified]
    #pragma unroll
    for (int m = 0; m < 2; ++m)
        #pragma unroll
        for (int n = 0; n < 8; ++n)
            #pragma unroll
            for (int i = 0; i < 4; ++i) {
                const int r = row0 + wave * 32 + m * 16 + kg * 4 + i;
                C[(size_t)r * HID + n * 16 + lr] = f2bf(acc[m][n][i]);
            }
}

// ---------------- GEMM for W4 [128,6], bf16 H ------------------------------
__global__ void gemm_w4(const unsigned short* __restrict__ H, const float* __restrict__ W,
                        float* __restrict__ S, int M) {
    __shared__ float Ws[HID * NCLS];
    for (int i = threadIdx.x; i < HID * NCLS; i += blockDim.x) Ws[i] = W[i];
    __syncthreads();
    const int r = blockIdx.x * blockDim.x + threadIdx.x;
    if (r >= M) return;
    float acc[NCLS] = {};
    const unsigned short* h = &H[(size_t)r * HID];
    for (int k0 = 0; k0 < HID; k0 += 8) {
        const uint4 hv = *reinterpret_cast<const uint4*>(&h[k0]);
        float hf[8];
        hf[0] = bflo(hv.x); hf[1] = bfhi(hv.x);
        hf[2] = bflo(hv.y); hf[3] = bfhi(hv.y);
        hf[4] = bflo(hv.z); hf[5] = bfhi(hv.z);
        hf[6] = bflo(hv.w); hf[7] = bfhi(hv.w);
        #pragma unroll
        for (int u = 0; u < 8; ++u)
            #pragma unroll
            for (int j = 0; j < NCLS; ++j)
                acc[j] = fmaf(hf[u], Ws[(k0 + u) * NCLS + j], acc[j]);
    }
    #pragma unroll
    for (int j = 0; j < NCLS; ++j) S[(size_t)r * NCLS + j] = acc[j];
}

// ================= CSR construction (rows padded to %8) ====================
__global__ void hist_k(const int* __restrict__ erow, int* __restrict__ cnt) {
    const int e = blockIdx.x * blockDim.x + threadIdx.x;
    if (e < NE) atomicAdd(&cnt[erow[e]], 1);
}

__global__ void scan1_k(const int* __restrict__ in, int* __restrict__ out,
                        int* __restrict__ bsum, int n) {
    __shared__ int s[256];
    const int tid = threadIdx.x;
    const int gid = blockIdx.x * 256 + tid;
    const int v = (gid < NN) ? ((in[gid] + 7) & ~7) : 0;
    s[tid] = v;
    __syncthreads();
    for (int off = 1; off < 256; off <<= 1) {
        const int t = (tid >= off) ? s[tid - off] : 0;
        __syncthreads();
        s[tid] += t;
        __syncthreads();
    }
    if (gid < n) out[gid] = s[tid] - v;
    if (tid == 255) bsum[blockIdx.x] = s[255];
}

__global__ void scan2_k(int* __restrict__ bsum, int nb) {
    __shared__ int s[512];
    const int tid = threadIdx.x;
    const int v = (tid < nb) ? bsum[tid] : 0;
    s[tid] = v;
    __syncthreads();
    for (int off = 1; off < 512; off <<= 1) {
        const int t = (tid >= off) ? s[tid - off] : 0;
        __syncthreads();
        s[tid] += t;
        __syncthreads();
    }
    if (tid < nb) bsum[tid] = s[tid] - v;
}

__global__ void scan3_k(int* __restrict__ out, const int* __restrict__ bsum, int n) {
    const int gid = blockIdx.x * 256 + threadIdx.x;
    if (gid < n) out[gid] += bsum[blockIdx.x];
}

__global__ void scatter_k(const int* __restrict__ erow, const int* __restrict__ ecol,
                          const float* __restrict__ ew,
                          const int* __restrict__ row_ptr, int* __restrict__ cur,
                          int2* __restrict__ edges) {
    const int e = blockIdx.x * blockDim.x + threadIdx.x;
    if (e >= NE) return;
    const int r = erow[e];
    const int pos = row_ptr[r] + atomicAdd(&cur[r], 1);
    edges[pos] = make_int2(ecol[e], __float_as_int(ew[e]));
}

// zero only the pad slots (cnt[r]..row_ptr[r+1])
__global__ void pad_k(const int* __restrict__ row_ptr, const int* __restrict__ cur,
                      int2* __restrict__ edges) {
    const int r = blockIdx.x * blockDim.x + threadIdx.x;
    if (r >= NN) return;
    const int end = row_ptr[r + 1];
    for (int p = row_ptr[r] + cur[r]; p < end; ++p) edges[p] = make_int2(0, 0);
}

// ============ CSR SpMM, F=128, bf16 in/out, 16-deep gather MLP =============
// 64 lanes per row: each edge gather = 256B contiguous (full S row), the
// whole-line-gather property that round-7 chunking destroyed.
template<bool RELU>
__launch_bounds__(256)
__global__ void spmm_bf16(const int* __restrict__ row_ptr,
                          const int2* __restrict__ edges,
                          const unsigned short* __restrict__ S,
                          const float* __restrict__ bias,
                          unsigned short* __restrict__ out) {
    const int lane = threadIdx.x & 63;
    const int row = blockIdx.x * 4 + (threadIdx.x >> 6);
    if (row >= NN) return;
    const int beg = row_ptr[row];
    const int end = row_ptr[row + 1];
    const int fo = lane * 2;
    float2 a0 = *reinterpret_cast<const float2*>(&bias[fo]);
    float2 a1 = {0.f, 0.f}, a2 = {0.f, 0.f}, a3 = {0.f, 0.f};

    int j = beg;
    // main: 16 edges/iter, 16 independent gathers in flight
    for (; j + 16 <= end; j += 16) {
        int4 p[8];
        #pragma unroll
        for (int q = 0; q < 8; ++q) p[q] = *reinterpret_cast<const int4*>(edges + j + 2 * q);
        uint32_t s[16];
        #pragma unroll
        for (int q = 0; q < 8; ++q) {
            s[2 * q]     = *reinterpret_cast<const uint32_t*>(&S[(size_t)p[q].x * HID + fo]);
            s[2 * q + 1] = *reinterpret_cast<const uint32_t*>(&S[(size_t)p[q].z * HID + fo]);
        }
        #pragma unroll
        for (int q = 0; q < 4; ++q) {
            const float w0 = __int_as_float(p[q].y), w1 = __int_as_float(p[q].w);
            const float w2 = __int_as_float(p[q + 4].y), w3 = __int_as_float(p[q + 4].w);
            a0.x = fmaf(bflo(s[2*q]),   w0, a0.x); a0.y = fmaf(bfhi(s[2*q]),   w0, a0.y);
            a1.x = fmaf(bflo(s[2*q+1]), w1, a1.x); a1.y = fmaf(bfhi(s[2*q+1]), w1, a1.y);
            a2.x = fmaf(bflo(s[2*q+8]), w2, a2.x); a2.y = fmaf(bfhi(s[2*q+8]), w2, a2.y);
            a3.x = fmaf(bflo(s[2*q+9]), w3, a3.x); a3.y = fmaf(bfhi(s[2*q+9]), w3, a3.y);
        }
    }
    // tail: 8 edges (rows are padded to %8)
    for (; j < end; j += 8) {
        int4 p[4];
        #pragma unroll
        for (int q = 0; q < 4; ++q) p[q] = *reinterpret_cast<const int4*>(edges + j + 2 * q);
        uint32_t s[8];
        #pragma unroll
        for (int q = 0; q < 4; ++q) {
            s[2 * q]     = *reinterpret_cast<const uint32_t*>(&S[(size_t)p[q].x * HID + fo]);
            s[2 * q + 1] = *reinterpret_cast<const uint32_t*>(&S[(size_t)p[q].z * HID + fo]);
        }
        #pragma unroll
        for (int q = 0; q < 2; ++q) {
            const float w0 = __int_as_float(p[q].y), w1 = __int_as_float(p[q].w);
            const float w2 = __int_as_float(p[q + 2].y), w3 = __int_as_float(p[q + 2].w);
            a0.x = fmaf(bflo(s[2*q]),   w0, a0.x); a0.y = fmaf(bfhi(s[2*q]),   w0, a0.y);
            a1.x = fmaf(bflo(s[2*q+1]), w1, a1.x); a1.y = fmaf(bfhi(s[2*q+1]), w1, a1.y);
            a2.x = fmaf(bflo(s[2*q+4]), w2, a2.x); a2.y = fmaf(bfhi(s[2*q+4]), w2, a2.y);
            a3.x = fmaf(bflo(s[2*q+5]), w3, a3.x); a3.y = fmaf(bfhi(s[2*q+5]), w3, a3.y);
        }
    }
    float fx = (a0.x + a1.x) + (a2.x + a3.x);
    float fy = (a0.y + a1.y) + (a2.y + a3.y);
    if (RELU) { fx = fmaxf(fx, 0.f); fy = fmaxf(fy, 0.f); }
    const uint32_t o = (uint32_t)f2bf(fx) | ((uint32_t)f2bf(fy) << 16);
    *reinterpret_cast<uint32_t*>(&out[(size_t)row * HID + fo]) = o;
}

// ============ CSR SpMM, F=6, fp32, 16 lanes/row ============================
__launch_bounds__(256)
__global__ void spmm6(const int* __restrict__ row_ptr,
                      const int2* __restrict__ edges,
                      const float* __restrict__ S,
                      const float* __restrict__ bias,
                      float* __restrict__ out) {
    const int t = blockIdx.x * blockDim.x + threadIdx.x;
    const int row = t >> 4;
    const int sl = t & 15;
    if (row >= NN) return;
    const int beg = row_ptr[row];
    const int end = row_ptr[row + 1];
    float acc[NCLS] = {};
    for (int j = beg + sl; j < end; j += 16) {
        const int2 e = edges[j];
        const float w = __int_as_float(e.y);
        const float* s = &S[(size_t)e.x * NCLS];
        #pragma unroll
        for (int k = 0; k < NCLS; ++k) acc[k] = fmaf(s[k], w, acc[k]);
    }
    #pragma unroll
    for (int off = 8; off > 0; off >>= 1)
        #pragma unroll
        for (int k = 0; k < NCLS; ++k) acc[k] += __shfl_xor(acc[k], off, 64);
    if (sl == 0) {
        #pragma unroll
        for (int k = 0; k < NCLS; ++k) out[(size_t)row * NCLS + k] = acc[k] + bias[k];
    }
}

extern "C" void kernel_launch(void* const* d_in, const int* in_sizes, int n_in,
                              void* d_out, int out_size, void* d_ws, size_t ws_size,
                              hipStream_t stream) {
    const float* x    = (const float*)d_in[0];
    const int*   erow = (const int*)d_in[1];
    const int*   ecol = (const int*)d_in[2];
    const float* ew   = (const float*)d_in[3];
    const float* W1 = (const float*)d_in[4];  const float* b1 = (const float*)d_in[5];
    const float* W2 = (const float*)d_in[6];  const float* b2 = (const float*)d_in[7];
    const float* W3 = (const float*)d_in[8];  const float* b3 = (const float*)d_in[9];
    const float* W4 = (const float*)d_in[10]; const float* b4 = (const float*)d_in[11];
    float* out = (float*)d_out;

    // ---- workspace layout ----
    int2*           edges_s = (int2*)d_ws;                          // EPAD*8B
    unsigned short* sup16   = (unsigned short*)(edges_s + EPAD);    // NN*128*2B (row-major)
    unsigned short* h16     = sup16 + (size_t)NN * HID;             // NN*128*2B (row-major)
    float*          sup6    = (float*)(h16 + (size_t)NN * HID);     // NN*6*4B
    unsigned short* Bp1     = (unsigned short*)(sup6 + (size_t)NN * NCLS);
    unsigned short* Bp2     = Bp1 + (size_t)FIN * HID;
    unsigned short* Bp3     = Bp2 + (size_t)HID * HID;
    int*            row_ptr = (int*)(Bp3 + (size_t)HID * HID);      // NN+1
    int*            row_cnt = row_ptr + (NN + 1);                   // NN (hist)
    int*            row_cur = row_cnt + NN;                         // NN (scatter cursor)
    int*            bsum    = row_cur + NN;                         // 512

    const dim3 blk(256);
    const int  g_edge = (NE + 255) / 256;
    const int  NB = (NN + 1 + 255) / 256;

    // ---- weights -> fragment-ordered bf16 ----
    cvt_w3<<<(12288 + 255) / 256, blk, 0, stream>>>(W1, W2, W3, Bp1, Bp2, Bp3);

    // ---- build CSR (rows padded to %8) ----
    hipMemsetAsync(row_cnt, 0, (size_t)2 * NN * sizeof(int), stream);  // cnt + cur
    hist_k<<<g_edge, blk, 0, stream>>>(erow, row_cnt);
    scan1_k<<<NB, blk, 0, stream>>>(row_cnt, row_ptr, bsum, NN + 1);
    scan2_k<<<1, 512, 0, stream>>>(bsum, NB);
    scan3_k<<<NB, blk, 0, stream>>>(row_ptr, bsum, NN + 1);
    scatter_k<<<g_edge, blk, 0, stream>>>(erow, ecol, ew, row_ptr, row_cur, edges_s);
    pad_k<<<(NN + 255) / 256, blk, 0, stream>>>(row_ptr, row_cur, edges_s);

    const int g_gemm = NN / 160;            // 625, exact
    const int g_spmm = NN / 4;

    // ---- layer 1 ----
    gemm_lds<FIN, false><<<g_gemm, dim3(320), 0, stream>>>(x, Bp1, sup16);
    spmm_bf16<true><<<g_spmm, blk, 0, stream>>>(row_ptr, edges_s, sup16, b1, h16);
    // ---- layer 2 ----
    gemm_lds<HID, true><<<g_gemm, dim3(320), 0, stream>>>(h16, Bp2, sup16);
    spmm_bf16<true><<<g_spmm, blk, 0, stream>>>(row_ptr, edges_s, sup16, b2, h16);
    // ---- layer 3 ----
    gemm_lds<HID, true><<<g_gemm, dim3(320), 0, stream>>>(h16, Bp3, sup16);
    spmm_bf16<true><<<g_spmm, blk, 0, stream>>>(row_ptr, edges_s, sup16, b3, h16);
    // ---- layer 4 ----
    gemm_w4<<<(NN + 255) / 256, blk, 0, stream>>>(h16, W4, sup6, NN);
    spmm6<<<(NN * 16 + 255) / 256, blk, 0, stream>>>(row_ptr, edges_s, sup6, b4, out);
}

// Round 9
// 449.572 us; speedup vs baseline: 1.2699x; 1.0218x over previous
//
#include <hip/hip_runtime.h>
#include <cstdint>

constexpr int NN = 100000;   // nodes
constexpr int NE = 1600000;  // edges
constexpr int FIN = 512;
constexpr int HID = 128;
constexpr int NCLS = 6;
constexpr int EPAD = NE + 3 * NN;   // upper bound on pad-to-4 CSR edges

typedef __attribute__((ext_vector_type(8))) short short8v;  // 8 bf16 (4 VGPR)
typedef __attribute__((ext_vector_type(4))) float f32x4;

constexpr float WINV = 1.0f / 32767.0f;

__device__ __forceinline__ unsigned short f2bf(float f) {
    uint32_t u = __float_as_uint(f);
    uint32_t r = u + 0x7FFFu + ((u >> 16) & 1u);   // round-to-nearest-even
    return (unsigned short)(r >> 16);
}
__device__ __forceinline__ float bflo(uint32_t u) { return __uint_as_float(u << 16); }
__device__ __forceinline__ float bfhi(uint32_t u) { return __uint_as_float(u & 0xffff0000u); }

// async global -> LDS, 16B per lane; lds dest must be wave-uniform base
__device__ __forceinline__ void gl_lds16(const void* g, void* l) {
    __builtin_amdgcn_global_load_lds(
        (const __attribute__((address_space(1))) unsigned int*)(unsigned long long)g,
        (__attribute__((address_space(3))) unsigned int*)(unsigned int)(unsigned long long)l,
        16, 0, 0);
}

// ============ W1/W2/W3 fp32 -> fragment-ordered bf16, one launch ===========
__device__ __forceinline__ void cvt_body(const float* __restrict__ W,
                                         unsigned short* __restrict__ Bp, int t) {
    const int lane = t & 63;
    const int fi = t >> 6;
    const int n = fi & 7, ks = fi >> 3;
    const int krow = ks * 32 + (lane >> 4) * 8;
    const int col = n * 16 + (lane & 15);
    short8v sv;
    #pragma unroll
    for (int j = 0; j < 8; ++j) sv[j] = (short)f2bf(W[(size_t)(krow + j) * HID + col]);
    *(short8v*)&Bp[(size_t)t * 8] = sv;
}

__global__ void cvt_w3(const float* __restrict__ W1, const float* __restrict__ W2,
                       const float* __restrict__ W3,
                       unsigned short* __restrict__ Bp1, unsigned short* __restrict__ Bp2,
                       unsigned short* __restrict__ Bp3) {
    const int t = blockIdx.x * blockDim.x + threadIdx.x;
    constexpr int T1 = (FIN / 32) * 8 * 64;       // 8192
    constexpr int T2 = (HID / 32) * 8 * 64;       // 2048
    if (t < T1)                cvt_body(W1, Bp1, t);
    else if (t < T1 + T2)      cvt_body(W2, Bp2, t - T1);
    else if (t < T1 + 2 * T2)  cvt_body(W3, Bp3, t - T1 - T2);
}

// ============ LDS-staged MFMA GEMM: C[M,128](bf16) = A[M,K] @ Bp ===========
// BM=160 rows/block, 5 waves x 32 rows, KS=32. Per-wave private LDS slices,
// NO barriers. B frags loaded FIRST each step so one counted vmcnt(NISS)
// covers B + current A buffer while next-tile DMAs stay in flight (T4).
template<int K, bool ABF>   // ABF: A is bf16 (else fp32)
__launch_bounds__(320)
__global__ void gemm_lds(const void* __restrict__ Av, const unsigned short* __restrict__ Bp,
                         unsigned short* __restrict__ C) {
    constexpr int BM    = 160;
    constexpr int KS    = 32;
    constexpr int EB    = ABF ? 2 : 4;       // element bytes
    constexpr int ROWB  = KS * EB;           // bytes per row window: 64 / 128
    constexpr int SLOTS = ROWB / 16;         // 4 / 8
    constexpr int SMSK  = SLOTS - 1;
    constexpr int CHUNK = BM * ROWB;         // 10240 / 20480
    constexpr int WBYT  = CHUNK / 5;         // bytes staged per wave: 2048 / 4096
    constexpr int NISS  = WBYT / 1024;       // DMA issues per wave per step: 2 / 4
    constexpr int NS    = K / KS;

    __shared__ __attribute__((aligned(16))) unsigned char lds[2 * CHUNK];

    const int tid  = threadIdx.x;
    const int lane = tid & 63;
    const int wave = tid >> 6;               // 0..4
    const int row0 = blockIdx.x * BM;
    const int lr   = lane & 15;
    const int kg   = lane >> 4;              // 0..3

    const unsigned char* Ab = (const unsigned char*)Av;
    const size_t rowbytes = (size_t)K * EB;

    // staging: per issue i, thread covers LDS byte Lw; src slot XOR-swizzled
    auto stage = [&](int bufsel, int ks) {
        const size_t kbyte = (size_t)ks * ROWB;
        #pragma unroll
        for (int i = 0; i < NISS; ++i) {
            const int Lw   = wave * WBYT + i * 1024 + lane * 16;
            const int row  = Lw / ROWB;
            const int slot = (Lw >> 4) & SMSK;
            const int src  = slot ^ (row & SMSK);
            const unsigned char* g = Ab + (size_t)(row0 + row) * rowbytes + kbyte + src * 16;
            void* l = (void*)&lds[bufsel * CHUNK + wave * WBYT + i * 1024];
            gl_lds16(g, l);
        }
    };

    f32x4 acc[2][8] = {};

    stage(0, 0);

    int cur = 0;
    for (int ks = 0; ks < NS; ++ks) {
        // ---- B fragments FIRST (so they're older than the stage DMAs) ----
        short8v bfr[8];
        const unsigned short* bb = Bp + ((size_t)ks * 8 * 64 + lane) * 8;
        #pragma unroll
        for (int n = 0; n < 8; ++n)
            bfr[n] = *reinterpret_cast<const short8v*>(bb + (size_t)n * 64 * 8);

        if (ks + 1 < NS) {
            stage(cur ^ 1, ks + 1);
            // drain everything except the NISS just-issued next-tile DMAs:
            // B frags of this step + current A buffer are then complete.
            asm volatile("s_waitcnt vmcnt(%0)" :: "i"(NISS) : "memory");
        } else {
            asm volatile("s_waitcnt vmcnt(0)" ::: "memory");
        }
        __builtin_amdgcn_sched_barrier(0);

        const unsigned char* base = &lds[cur * CHUNK];
        const int rA0 = wave * 32 + lr;
        const int rA1 = rA0 + 16;
        const int key = lr & SMSK;           // (rA0 & SMSK) == (rA1 & SMSK)

        short8v a0, a1;
        if constexpr (ABF) {
            a0 = *(const short8v*)(base + rA0 * ROWB + ((kg ^ key) * 16));
            a1 = *(const short8v*)(base + rA1 * ROWB + ((kg ^ key) * 16));
        } else {
            const float4 f00 = *(const float4*)(base + rA0 * ROWB + (((2 * kg + 0) ^ key) * 16));
            const float4 f01 = *(const float4*)(base + rA0 * ROWB + (((2 * kg + 1) ^ key) * 16));
            const float4 f10 = *(const float4*)(base + rA1 * ROWB + (((2 * kg + 0) ^ key) * 16));
            const float4 f11 = *(const float4*)(base + rA1 * ROWB + (((2 * kg + 1) ^ key) * 16));
            a0[0] = (short)f2bf(f00.x); a0[1] = (short)f2bf(f00.y);
            a0[2] = (short)f2bf(f00.z); a0[3] = (short)f2bf(f00.w);
            a0[4] = (short)f2bf(f01.x); a0[5] = (short)f2bf(f01.y);
            a0[6] = (short)f2bf(f01.z); a0[7] = (short)f2bf(f01.w);
            a1[0] = (short)f2bf(f10.x); a1[1] = (short)f2bf(f10.y);
            a1[2] = (short)f2bf(f10.z); a1[3] = (short)f2bf(f10.w);
            a1[4] = (short)f2bf(f11.x); a1[5] = (short)f2bf(f11.y);
            a1[6] = (short)f2bf(f11.z); a1[7] = (short)f2bf(f11.w);
        }

        #pragma unroll
        for (int n = 0; n < 8; ++n) {
            acc[0][n] = __builtin_amdgcn_mfma_f32_16x16x32_bf16(a0, bfr[n], acc[0][n], 0, 0, 0);
            acc[1][n] = __builtin_amdgcn_mfma_f32_16x16x32_bf16(a1, bfr[n], acc[1][n], 0, 0, 0);
        }
        cur ^= 1;
    }

    // C/D layout: col = lane&15, row = (lane>>4)*4 + reg   [m89-verified]
    #pragma unroll
    for (int m = 0; m < 2; ++m)
        #pragma unroll
        for (int n = 0; n < 8; ++n)
            #pragma unroll
            for (int i = 0; i < 4; ++i) {
                const int r = row0 + wave * 32 + m * 16 + kg * 4 + i;
                C[(size_t)r * HID + n * 16 + lr] = f2bf(acc[m][n][i]);
            }
}

// ---------------- GEMM for W4 [128,6], bf16 H ------------------------------
__global__ void gemm_w4(const unsigned short* __restrict__ H, const float* __restrict__ W,
                        float* __restrict__ S, int M) {
    __shared__ float Ws[HID * NCLS];
    for (int i = threadIdx.x; i < HID * NCLS; i += blockDim.x) Ws[i] = W[i];
    __syncthreads();
    const int r = blockIdx.x * blockDim.x + threadIdx.x;
    if (r >= M) return;
    float acc[NCLS] = {};
    const unsigned short* h = &H[(size_t)r * HID];
    for (int k0 = 0; k0 < HID; k0 += 8) {
        const uint4 hv = *reinterpret_cast<const uint4*>(&h[k0]);
        float hf[8];
        hf[0] = bflo(hv.x); hf[1] = bfhi(hv.x);
        hf[2] = bflo(hv.y); hf[3] = bfhi(hv.y);
        hf[4] = bflo(hv.z); hf[5] = bfhi(hv.z);
        hf[6] = bflo(hv.w); hf[7] = bfhi(hv.w);
        #pragma unroll
        for (int u = 0; u < 8; ++u)
            #pragma unroll
            for (int j = 0; j < NCLS; ++j)
                acc[j] = fmaf(hf[u], Ws[(k0 + u) * NCLS + j], acc[j]);
    }
    #pragma unroll
    for (int j = 0; j < NCLS; ++j) S[(size_t)r * NCLS + j] = acc[j];
}

// ================= CSR construction (rows padded to %4, packed 4B edges) ===
// edge word = (col << 15) | round(w * 32767); w in [0,1) -> <=1.5e-5 abs err
__global__ void hist_k(const int* __restrict__ erow, int* __restrict__ cnt) {
    const int e = blockIdx.x * blockDim.x + threadIdx.x;
    if (e < NE) atomicAdd(&cnt[erow[e]], 1);
}

__global__ void scan1_k(const int* __restrict__ in, int* __restrict__ out,
                        int* __restrict__ bsum, int n) {
    __shared__ int s[256];
    const int tid = threadIdx.x;
    const int gid = blockIdx.x * 256 + tid;
    const int v = (gid < NN) ? ((in[gid] + 3) & ~3) : 0;
    s[tid] = v;
    __syncthreads();
    for (int off = 1; off < 256; off <<= 1) {
        const int t = (tid >= off) ? s[tid - off] : 0;
        __syncthreads();
        s[tid] += t;
        __syncthreads();
    }
    if (gid < n) out[gid] = s[tid] - v;
    if (tid == 255) bsum[blockIdx.x] = s[255];
}

__global__ void scan2_k(int* __restrict__ bsum, int nb) {
    __shared__ int s[512];
    const int tid = threadIdx.x;
    const int v = (tid < nb) ? bsum[tid] : 0;
    s[tid] = v;
    __syncthreads();
    for (int off = 1; off < 512; off <<= 1) {
        const int t = (tid >= off) ? s[tid - off] : 0;
        __syncthreads();
        s[tid] += t;
        __syncthreads();
    }
    if (tid < nb) bsum[tid] = s[tid] - v;
}

__global__ void scan3_k(int* __restrict__ out, const int* __restrict__ bsum, int n) {
    const int gid = blockIdx.x * 256 + threadIdx.x;
    if (gid < n) out[gid] += bsum[blockIdx.x];
}

__global__ void scatter_k(const int* __restrict__ erow, const int* __restrict__ ecol,
                          const float* __restrict__ ew,
                          const int* __restrict__ row_ptr, int* __restrict__ cur,
                          uint32_t* __restrict__ edges) {
    const int e = blockIdx.x * blockDim.x + threadIdx.x;
    if (e >= NE) return;
    const int r = erow[e];
    const int pos = row_ptr[r] + atomicAdd(&cur[r], 1);
    const uint32_t wq = (uint32_t)(ew[e] * 32767.0f + 0.5f);
    edges[pos] = ((uint32_t)ecol[e] << 15) | wq;
}

// zero only the pad slots (cnt[r]..row_ptr[r+1])
__global__ void pad_k(const int* __restrict__ row_ptr, const int* __restrict__ cur,
                      uint32_t* __restrict__ edges) {
    const int r = blockIdx.x * blockDim.x + threadIdx.x;
    if (r >= NN) return;
    const int end = row_ptr[r + 1];
    for (int p = row_ptr[r] + cur[r]; p < end; ++p) edges[p] = 0u;
}

// ============ CSR SpMM, F=128, bf16 in/out, 16-deep gather MLP =============
// 64 lanes per row: each edge gather = 256B contiguous (full S row).
// Packed 4B edges: uint4 load = 4 edges. Rows padded to %4.
template<bool RELU>
__launch_bounds__(256)
__global__ void spmm_bf16(const int* __restrict__ row_ptr,
                          const uint32_t* __restrict__ edges,
                          const unsigned short* __restrict__ S,
                          const float* __restrict__ bias,
                          unsigned short* __restrict__ out) {
    const int lane = threadIdx.x & 63;
    const int row = blockIdx.x * 4 + (threadIdx.x >> 6);
    if (row >= NN) return;
    const int beg = row_ptr[row];
    const int end = row_ptr[row + 1];
    const int fo = lane * 2;
    float2 a0 = *reinterpret_cast<const float2*>(&bias[fo]);
    float2 a1 = {0.f, 0.f}, a2 = {0.f, 0.f}, a3 = {0.f, 0.f};

    int j = beg;
    // main: 16 edges/iter, 16 independent gathers in flight
    for (; j + 16 <= end; j += 16) {
        uint4 e0 = *reinterpret_cast<const uint4*>(edges + j);
        uint4 e1 = *reinterpret_cast<const uint4*>(edges + j + 4);
        uint4 e2 = *reinterpret_cast<const uint4*>(edges + j + 8);
        uint4 e3 = *reinterpret_cast<const uint4*>(edges + j + 12);
        const uint32_t ea[16] = {e0.x, e0.y, e0.z, e0.w, e1.x, e1.y, e1.z, e1.w,
                                 e2.x, e2.y, e2.z, e2.w, e3.x, e3.y, e3.z, e3.w};
        uint32_t s[16];
        #pragma unroll
        for (int q = 0; q < 16; ++q)
            s[q] = *reinterpret_cast<const uint32_t*>(&S[(size_t)(ea[q] >> 15) * HID + fo]);
        #pragma unroll
        for (int q = 0; q < 4; ++q) {
            const float w0 = (float)(ea[q]      & 0x7FFFu) * WINV;
            const float w1 = (float)(ea[q + 4]  & 0x7FFFu) * WINV;
            const float w2 = (float)(ea[q + 8]  & 0x7FFFu) * WINV;
            const float w3 = (float)(ea[q + 12] & 0x7FFFu) * WINV;
            a0.x = fmaf(bflo(s[q]),      w0, a0.x); a0.y = fmaf(bfhi(s[q]),      w0, a0.y);
            a1.x = fmaf(bflo(s[q + 4]),  w1, a1.x); a1.y = fmaf(bfhi(s[q + 4]),  w1, a1.y);
            a2.x = fmaf(bflo(s[q + 8]),  w2, a2.x); a2.y = fmaf(bfhi(s[q + 8]),  w2, a2.y);
            a3.x = fmaf(bflo(s[q + 12]), w3, a3.x); a3.y = fmaf(bfhi(s[q + 12]), w3, a3.y);
        }
    }
    // tail: 4 edges/iter (rows padded to %4)
    for (; j < end; j += 4) {
        const uint4 e = *reinterpret_cast<const uint4*>(edges + j);
        const uint32_t ea[4] = {e.x, e.y, e.z, e.w};
        uint32_t s[4];
        #pragma unroll
        for (int q = 0; q < 4; ++q)
            s[q] = *reinterpret_cast<const uint32_t*>(&S[(size_t)(ea[q] >> 15) * HID + fo]);
        const float w0 = (float)(ea[0] & 0x7FFFu) * WINV;
        const float w1 = (float)(ea[1] & 0x7FFFu) * WINV;
        const float w2 = (float)(ea[2] & 0x7FFFu) * WINV;
        const float w3 = (float)(ea[3] & 0x7FFFu) * WINV;
        a0.x = fmaf(bflo(s[0]), w0, a0.x); a0.y = fmaf(bfhi(s[0]), w0, a0.y);
        a1.x = fmaf(bflo(s[1]), w1, a1.x); a1.y = fmaf(bfhi(s[1]), w1, a1.y);
        a2.x = fmaf(bflo(s[2]), w2, a2.x); a2.y = fmaf(bfhi(s[2]), w2, a2.y);
        a3.x = fmaf(bflo(s[3]), w3, a3.x); a3.y = fmaf(bfhi(s[3]), w3, a3.y);
    }
    float fx = (a0.x + a1.x) + (a2.x + a3.x);
    float fy = (a0.y + a1.y) + (a2.y + a3.y);
    if (RELU) { fx = fmaxf(fx, 0.f); fy = fmaxf(fy, 0.f); }
    const uint32_t o = (uint32_t)f2bf(fx) | ((uint32_t)f2bf(fy) << 16);
    *reinterpret_cast<uint32_t*>(&out[(size_t)row * HID + fo]) = o;
}

// ============ CSR SpMM, F=6, fp32, 16 lanes/row ============================
__launch_bounds__(256)
__global__ void spmm6(const int* __restrict__ row_ptr,
                      const uint32_t* __restrict__ edges,
                      const float* __restrict__ S,
                      const float* __restrict__ bias,
                      float* __restrict__ out) {
    const int t = blockIdx.x * blockDim.x + threadIdx.x;
    const int row = t >> 4;
    const int sl = t & 15;
    if (row >= NN) return;
    const int beg = row_ptr[row];
    const int end = row_ptr[row + 1];
    float acc[NCLS] = {};
    for (int j = beg + sl; j < end; j += 16) {
        const uint32_t e = edges[j];
        const float w = (float)(e & 0x7FFFu) * WINV;
        const float* s = &S[(size_t)(e >> 15) * NCLS];
        #pragma unroll
        for (int k = 0; k < NCLS; ++k) acc[k] = fmaf(s[k], w, acc[k]);
    }
    #pragma unroll
    for (int off = 8; off > 0; off >>= 1)
        #pragma unroll
        for (int k = 0; k < NCLS; ++k) acc[k] += __shfl_xor(acc[k], off, 64);
    if (sl == 0) {
        #pragma unroll
        for (int k = 0; k < NCLS; ++k) out[(size_t)row * NCLS + k] = acc[k] + bias[k];
    }
}

extern "C" void kernel_launch(void* const* d_in, const int* in_sizes, int n_in,
                              void* d_out, int out_size, void* d_ws, size_t ws_size,
                              hipStream_t stream) {
    const float* x    = (const float*)d_in[0];
    const int*   erow = (const int*)d_in[1];
    const int*   ecol = (const int*)d_in[2];
    const float* ew   = (const float*)d_in[3];
    const float* W1 = (const float*)d_in[4];  const float* b1 = (const float*)d_in[5];
    const float* W2 = (const float*)d_in[6];  const float* b2 = (const float*)d_in[7];
    const float* W3 = (const float*)d_in[8];  const float* b3 = (const float*)d_in[9];
    const float* W4 = (const float*)d_in[10]; const float* b4 = (const float*)d_in[11];
    float* out = (float*)d_out;

    // ---- workspace layout ----
    uint32_t*       edges_s = (uint32_t*)d_ws;                      // EPAD*4B
    unsigned short* sup16   = (unsigned short*)(edges_s + EPAD);    // NN*128*2B (row-major)
    unsigned short* h16     = sup16 + (size_t)NN * HID;             // NN*128*2B (row-major)
    float*          sup6    = (float*)(h16 + (size_t)NN * HID);     // NN*6*4B
    unsigned short* Bp1     = (unsigned short*)(sup6 + (size_t)NN * NCLS);
    unsigned short* Bp2     = Bp1 + (size_t)FIN * HID;
    unsigned short* Bp3     = Bp2 + (size_t)HID * HID;
    int*            row_ptr = (int*)(Bp3 + (size_t)HID * HID);      // NN+1
    int*            row_cnt = row_ptr + (NN + 1);                   // NN (hist)
    int*            row_cur = row_cnt + NN;                         // NN (scatter cursor)
    int*            bsum    = row_cur + NN;                         // 512

    const dim3 blk(256);
    const int  g_edge = (NE + 255) / 256;
    const int  NB = (NN + 1 + 255) / 256;

    // ---- weights -> fragment-ordered bf16 ----
    cvt_w3<<<(12288 + 255) / 256, blk, 0, stream>>>(W1, W2, W3, Bp1, Bp2, Bp3);

    // ---- build CSR (rows padded to %4; packed 4B edges) ----
    hipMemsetAsync(row_cnt, 0, (size_t)2 * NN * sizeof(int), stream);  // cnt + cur
    hist_k<<<g_edge, blk, 0, stream>>>(erow, row_cnt);
    scan1_k<<<NB, blk, 0, stream>>>(row_cnt, row_ptr, bsum, NN + 1);
    scan2_k<<<1, 512, 0, stream>>>(bsum, NB);
    scan3_k<<<NB, blk, 0, stream>>>(row_ptr, bsum, NN + 1);
    scatter_k<<<g_edge, blk, 0, stream>>>(erow, ecol, ew, row_ptr, row_cur, edges_s);
    pad_k<<<(NN + 255) / 256, blk, 0, stream>>>(row_ptr, row_cur, edges_s);

    const int g_gemm = NN / 160;            // 625, exact
    const int g_spmm = NN / 4;

    // ---- layer 1 ----
    gemm_lds<FIN, false><<<g_gemm, dim3(320), 0, stream>>>(x, Bp1, sup16);
    spmm_bf16<true><<<g_spmm, blk, 0, stream>>>(row_ptr, edges_s, sup16, b1, h16);
    // ---- layer 2 ----
    gemm_lds<HID, true><<<g_gemm, dim3(320), 0, stream>>>(h16, Bp2, sup16);
    spmm_bf16<true><<<g_spmm, blk, 0, stream>>>(row_ptr, edges_s, sup16, b2, h16);
    // ---- layer 3 ----
    gemm_lds<HID, true><<<g_gemm, dim3(320), 0, stream>>>(h16, Bp3, sup16);
    spmm_bf16<true><<<g_spmm, blk, 0, stream>>>(row_ptr, edges_s, sup16, b3, h16);
    // ---- layer 4 ----
    gemm_w4<<<(NN + 255) / 256, blk, 0, stream>>>(h16, W4, sup6, NN);
    spmm6<<<(NN * 16 + 255) / 256, blk, 0, stream>>>(row_ptr, edges_s, sup6, b4, out);
}